// Round 1
// baseline (176.517 us; speedup 1.0000x reference)
//
#include <hip/hip_runtime.h>
#include <stdint.h>

#define Bn 256
#define Tn 50
#define Mn 20
#define En 128
#define G3 384
#define MT 64
#define LDA 132

__device__ __forceinline__ float sigmoidf(float x) {
    return 1.0f / (1.0f + __expf(-x));
}
__device__ __forceinline__ float tanh_safe(float a) {
    float ax = fabsf(a);
    float e2 = __expf(-2.0f * ax);
    return copysignf((1.0f - e2) / (1.0f + e2), a);
}

// ---------------------------------------------------------------------------
// Kernel 1: basket-mean gather -> ub [B*T][128]  (stored in d_out region)
// ---------------------------------------------------------------------------
__global__ __launch_bounds__(256) void gather_kernel(
    const int*   __restrict__ item_ids,
    const int*   __restrict__ basket_sizes,
    const float* __restrict__ emb,
    float* __restrict__ ub)
{
    const int bt   = blockIdx.x * 8 + (threadIdx.x >> 5);
    const int lane = threadIdx.x & 31;
    const int* ids = item_ids + (size_t)bt * Mn;
    float ax = 0.f, ay = 0.f, az = 0.f, aw = 0.f;
    #pragma unroll
    for (int m = 0; m < Mn; ++m) {
        const float4 v = *(const float4*)(emb + (size_t)ids[m] * En + lane * 4);
        ax += v.x; ay += v.y; az += v.z; aw += v.w;
    }
    const float inv = 1.0f / (float)basket_sizes[bt];
    *(float4*)(ub + (size_t)bt * En + lane * 4) =
        make_float4(ax * inv, ay * inv, az * inv, aw * inv);
}

// ---------------------------------------------------------------------------
// Kernel 2: xg = ub @ W_ih^T + b_ih.  1200 blocks (200 M x 6 N); 4x4 tile.
// ---------------------------------------------------------------------------
__global__ __launch_bounds__(256, 2) void gemm_kernel(
    const float* __restrict__ ub,
    const float* __restrict__ W_ih,
    const float* __restrict__ b_ih,
    float* __restrict__ xg)
{
    __shared__ float A[MT][LDA];
    __shared__ float Bt[64][LDA];

    const int tid  = threadIdx.x;
    const int mt   = blockIdx.x / 6;
    const int nc   = blockIdx.x % 6;
    const int row0 = mt * MT;
    const int col0 = nc * 64;

    {
        const int r = tid >> 2, seg = tid & 3;
        const float4* srcA = (const float4*)(ub + (size_t)(row0 + r) * En + seg * 32);
        const float4* srcB = (const float4*)(W_ih + (size_t)(col0 + r) * En + seg * 32);
        float4* dstA = (float4*)&A[r][seg * 32];
        float4* dstB = (float4*)&Bt[r][seg * 32];
        #pragma unroll
        for (int c = 0; c < 8; ++c) { dstA[c] = srcA[c]; dstB[c] = srcB[c]; }
    }
    __syncthreads();

    const int tx = tid & 15;
    const int ty = tid >> 4;

    float acc[4][4];
    #pragma unroll
    for (int i = 0; i < 4; ++i)
        #pragma unroll
        for (int u = 0; u < 4; ++u) acc[i][u] = 0.0f;

    #pragma unroll 4
    for (int k4 = 0; k4 < 32; ++k4) {
        const float4 av[4] = {
            *(const float4*)&A[ty +  0][k4*4], *(const float4*)&A[ty + 16][k4*4],
            *(const float4*)&A[ty + 32][k4*4], *(const float4*)&A[ty + 48][k4*4]};
        const float4 bv[4] = {
            *(const float4*)&Bt[tx +  0][k4*4], *(const float4*)&Bt[tx + 16][k4*4],
            *(const float4*)&Bt[tx + 32][k4*4], *(const float4*)&Bt[tx + 48][k4*4]};
        #pragma unroll
        for (int i = 0; i < 4; ++i)
            #pragma unroll
            for (int u = 0; u < 4; ++u) {
                acc[i][u] = fmaf(av[i].x, bv[u].x, acc[i][u]);
                acc[i][u] = fmaf(av[i].y, bv[u].y, acc[i][u]);
                acc[i][u] = fmaf(av[i].z, bv[u].z, acc[i][u]);
                acc[i][u] = fmaf(av[i].w, bv[u].w, acc[i][u]);
            }
    }

    float bias[4];
    #pragma unroll
    for (int u = 0; u < 4; ++u) bias[u] = b_ih[col0 + tx + 16*u];
    #pragma unroll
    for (int i = 0; i < 4; ++i) {
        const size_t rowoff = (size_t)(row0 + ty + 16*i) * G3;
        #pragma unroll
        for (int u = 0; u < 4; ++u)
            xg[rowoff + col0 + tx + 16*u] = acc[i][u] + bias[u];
    }
}

// ---------------------------------------------------------------------------
// Kernel 3: sequential GRU. 256 blocks x 512 threads (8 waves, 2/SIMD).
// Thread (j in [0,128), q in [0,4)) owns gate rows {j, 128+j, 256+j} of W_hh,
// cols [q*32, q*32+32) -> 96 weight floats in SROA float4[8] arrays.
// K-reduction is IN-WAVE (shfl_xor over q, lanes 1 and 2 apart) -> no
// cross-wave phase-B, no reduction LDS. All 4 q-lanes redundantly compute the
// gates, so h_new is available in-register everywhere. hs is double-buffered
// -> exactly ONE __syncthreads per step across only 8 waves.
// The q-dependent rotation (c+2q)&7 of the K-slice walk (applied identically
// to the weight LOADS so register indices stay compile-time) makes the four
// q-groups' ds_read_b128 hit disjoint bank quads (a 128-float h row wraps the
// 32 banks exactly, so unrotated all q slices start at bank 0 -> 4-way).
// ---------------------------------------------------------------------------
__global__ __launch_bounds__(512, 2) void gru_kernel(
    const int*   __restrict__ lengths,
    const float* __restrict__ W_hh,
    const float* __restrict__ b_hh,
    const float* __restrict__ h0,
    const float* __restrict__ xg,
    float* __restrict__ out_dyn,
    float* __restrict__ out_h)
{
    __shared__ float hs[2][En];

    const int tid = threadIdx.x;
    const int b   = blockIdx.x;
    const int j   = tid >> 2;        // [0,128)
    const int q   = tid & 3;         // [0,4) — low lane bits: shfl_xor stays in-wave

    // Weight fragments, rotated by q at load time so compute indices are constant.
    float4 w0[8], w1[8], w2[8];
    {
        const float4* p0 = (const float4*)(W_hh + (size_t)(0*En + j) * En + q * 32);
        const float4* p1 = (const float4*)(W_hh + (size_t)(1*En + j) * En + q * 32);
        const float4* p2 = (const float4*)(W_hh + (size_t)(2*En + j) * En + q * 32);
        #pragma unroll
        for (int c = 0; c < 8; ++c) {
            const int cc = (c + 2*q) & 7;
            w0[c] = p0[cc]; w1[c] = p1[cc]; w2[c] = p2[cc];
        }
    }

    const int len = lengths[b];
    const float* xgb = xg + (size_t)b * Tn * G3;
    float* outb = out_dyn + (size_t)b * Tn * En;

    const float br = b_hh[j], bz = b_hh[En + j], bn = b_hh[2*En + j];
    float hprev = h0[(size_t)b * En + j];
    if (q == 0) hs[0][j] = hprev;
    float xr = xgb[j], xz = xgb[En + j], xn = xgb[2*En + j];
    __syncthreads();

    int cur = 0;
    for (int t = 0; t < len; ++t) {
        // partial dots over this thread's 32-col K-slice (broadcast LDS reads,
        // bank-conflict-free via the rotated walk)
        const float4* h4 = ((const float4*)hs[cur]) + q * 8;
        float a0 = 0.f, a1 = 0.f, a2 = 0.f;
        #pragma unroll
        for (int c = 0; c < 8; ++c) {
            const float4 hv = h4[(c + 2*q) & 7];
            a0 = fmaf(w0[c].x, hv.x, a0); a0 = fmaf(w0[c].y, hv.y, a0);
            a0 = fmaf(w0[c].z, hv.z, a0); a0 = fmaf(w0[c].w, hv.w, a0);
            a1 = fmaf(w1[c].x, hv.x, a1); a1 = fmaf(w1[c].y, hv.y, a1);
            a1 = fmaf(w1[c].z, hv.z, a1); a1 = fmaf(w1[c].w, hv.w, a1);
            a2 = fmaf(w2[c].x, hv.x, a2); a2 = fmaf(w2[c].y, hv.y, a2);
            a2 = fmaf(w2[c].z, hv.z, a2); a2 = fmaf(w2[c].w, hv.w, a2);
        }

        // prefetch next step's xg (latency hidden under FMAs + barrier)
        const int tn = (t + 1 < len) ? t + 1 : t;
        const float nxr = xgb[tn*G3 + j];
        const float nxz = xgb[tn*G3 + En + j];
        const float nxn = xgb[tn*G3 + 2*En + j];

        // in-wave butterfly reduce over q (lanes 1, 2 apart)
        a0 += __shfl_xor(a0, 1); a0 += __shfl_xor(a0, 2);
        a1 += __shfl_xor(a1, 1); a1 += __shfl_xor(a1, 2);
        a2 += __shfl_xor(a2, 1); a2 += __shfl_xor(a2, 2);

        // gates — computed redundantly by all 4 q-lanes (zero extra latency)
        const float r = sigmoidf(xr + br + a0);
        const float z = sigmoidf(xz + bz + a1);
        const float n = tanh_safe(xn + r * (bn + a2));
        const float hnew = (1.0f - z) * n + z * hprev;

        if (q == 0) {
            hs[cur ^ 1][j] = hnew;      // write the OTHER buffer: no read-write hazard
            outb[t*En + j] = hnew;
        }
        __syncthreads();                // single barrier per step
        hprev = hnew;
        xr = nxr; xz = nxz; xn = nxn;
        cur ^= 1;
    }

    if (q == 0) {
        for (int t = len; t < Tn; ++t) outb[t*En + j] = 0.0f;
        out_h[(size_t)b * En + j] = hprev;
    }
}

extern "C" void kernel_launch(void* const* d_in, const int* in_sizes, int n_in,
                              void* d_out, int out_size, void* d_ws, size_t ws_size,
                              hipStream_t stream) {
    const int*   item_ids     = (const int*)d_in[0];
    const int*   basket_sizes = (const int*)d_in[1];
    const int*   lengths      = (const int*)d_in[2];
    const float* emb          = (const float*)d_in[3];
    const float* W_ih         = (const float*)d_in[4];
    const float* W_hh         = (const float*)d_in[5];
    const float* b_ih         = (const float*)d_in[6];
    const float* b_hh         = (const float*)d_in[7];
    const float* h0           = (const float*)d_in[8];
    float* out = (float*)d_out;
    float* xg  = (float*)d_ws;   // 19.7 MB
    float* ub  = out;            // reuse out_dyn region; overwritten by gru later

    gather_kernel<<<(Bn * Tn) / 8, 256, 0, stream>>>(item_ids, basket_sizes, emb, ub);
    gemm_kernel<<<1200, 256, 0, stream>>>(ub, W_ih, b_ih, xg);
    gru_kernel<<<Bn, 512, 0, stream>>>(
        lengths, W_hh, b_hh, h0, xg, out, out + (size_t)Bn * Tn * En);
}